// Round 2
// baseline (490.202 us; speedup 1.0000x reference)
//
#include <hip/hip_runtime.h>
#include <stdint.h>
#include <stddef.h>

// Problem constants (MultiHeadAttention_52759378264454)
constexpr int T_SEQ = 1024;
constexpr int BATCH = 8;
constexpr int DIN   = 256;
constexpr int NH    = 8;
constexpr int EH    = 512;
constexpr int HE    = NH * EH;   // 4096
constexpr float SCALE = 0.044194173824159216f; // 1/sqrt(512)

typedef __attribute__((ext_vector_type(8))) short s16x8;
typedef __attribute__((ext_vector_type(4))) short s16x4;
typedef __attribute__((ext_vector_type(4))) float f32x4_t;

__device__ __forceinline__ short f2bf(float f) {
  union { float f; uint32_t u; } c; c.f = f;
  uint32_t u = c.u;
  u += 0x7fffu + ((u >> 16) & 1u);   // RNE (finite values only here)
  return (short)(u >> 16);
}
__device__ __forceinline__ float bf2f(short s) {
  union { uint32_t u; float f; } c; c.u = ((uint32_t)(uint16_t)s) << 16;
  return c.f;
}

// async global->LDS, 16B per lane. LDS dest = wave-uniform base + lane*16 (HW).
__device__ __forceinline__ void gload16(const short* g, short* l) {
  __builtin_amdgcn_global_load_lds(
      (__attribute__((address_space(1))) void*)(void*)const_cast<short*>(g),
      (__attribute__((address_space(3))) void*)(void*)l, 16, 0, 0);
}

#define WAITVM8 asm volatile("s_waitcnt vmcnt(8) lgkmcnt(0)" ::: "memory")
#define WAITVM4 asm volatile("s_waitcnt vmcnt(4) lgkmcnt(0)" ::: "memory")
#define WAITVM0 asm volatile("s_waitcnt vmcnt(0) lgkmcnt(0)" ::: "memory")
#define CFENCE  asm volatile("" ::: "memory")

// ---------------------------------------------------------------------------
// 8-wave 256x256 tile GEMM core, BK=32, 4-slot circular LDS pipeline.
// C[BM=256, BN=256] += A[256,K] * B[256,K]^T, both K-major bf16.
// 512 threads = 8 waves: wave_m = wv>>2 (2), wave_n = wv&3 (4).
// Per wave: 128x64 output = 8x4 frags of 16x16, MFMA 16x16x32.
// LDS slot = A[256][32] + B[256][32] bf16 = 32 KiB; 4 slots = 128 KiB (dynamic).
// Swizzle: 16B-chunk index within 64B row: cp ^= (row&3) ^ ((row>>2)&3)
//   (applied on pre-swizzled global source AND on ds_read -> 2-way max).
// Pipeline: tiles t+1, t+2 in flight (8 loads) across every barrier;
//   issue tile t+3 (slot (t-1)&3, freed at this phase's barrier) after barrier.
// ---------------------------------------------------------------------------
template<int NT>
__device__ __forceinline__ void gemm8w(const short* __restrict__ Ag, int lda,
                                       const short* __restrict__ Bg, int ldb,
                                       short* lds, f32x4_t (&acc)[8][4])
{
  const int tid  = threadIdx.x;
  const int lane = tid & 63;
  const int wv   = tid >> 6;
  const int g    = lane >> 4, r = lane & 15;
  const int Rw   = (wv >> 2) * 128;
  const int Cw   = (wv & 3) * 64;

  // read-side swizzled chunk offset (independent of frag index: row = k*16 + r)
  const int cp8  = (g ^ (r & 3) ^ ((r >> 2) & 3)) * 8;
  const int aoff = (Rw + r) * 32 + cp8;          // shorts; + mi*512
  const int boff = 8192 + (Cw + r) * 32 + cp8;   // shorts; + ni*512

  // stage-side: thread covers 16B chunks (tid + j*512) of A and of B
  const short* srcA[2]; const short* srcB[2];
  int dstA[2], dstB[2];
#pragma unroll
  for (int j = 0; j < 2; ++j) {
    int c    = tid + j * 512;
    int row  = c >> 2, cp = c & 3;
    int scol = cp ^ (row & 3) ^ ((row >> 2) & 3);   // involution
    srcA[j] = Ag + (size_t)row * lda + scol * 8;
    srcB[j] = Bg + (size_t)row * ldb + scol * 8;
    dstA[j] = (wv * 64 + j * 512) * 8;              // wave-uniform LDS base
    dstB[j] = 8192 + (wv * 64 + j * 512) * 8;
  }

  auto issue = [&](int t) {
    short* sl = lds + (t & 3) * 16384;
    const int kc = t * 32;
#pragma unroll
    for (int j = 0; j < 2; ++j) gload16(srcA[j] + kc, sl + dstA[j]);
#pragma unroll
    for (int j = 0; j < 2; ++j) gload16(srcB[j] + kc, sl + dstB[j]);
  };

  auto compute = [&](int t) {
    const short* sl = lds + (t & 3) * 16384;
    s16x8 av[8], bv[4];
#pragma unroll
    for (int ni = 0; ni < 4; ++ni) bv[ni] = *(const s16x8*)(sl + boff + ni * 512);
#pragma unroll
    for (int mi = 0; mi < 8; ++mi) av[mi] = *(const s16x8*)(sl + aoff + mi * 512);
    __builtin_amdgcn_s_setprio(1);
#pragma unroll
    for (int mi = 0; mi < 8; ++mi)
#pragma unroll
      for (int ni = 0; ni < 4; ++ni)
        acc[mi][ni] = __builtin_amdgcn_mfma_f32_16x16x32_bf16(av[mi], bv[ni], acc[mi][ni], 0, 0, 0);
    __builtin_amdgcn_s_setprio(0);
  };

  issue(0); issue(1); issue(2);     // NT >= 4 for all users
#pragma unroll 1
  for (int t = 0; t < NT - 2; ++t) {
    WAITVM8;                        // own tile-t loads landed; 8 newest stay in flight
    __builtin_amdgcn_s_barrier();   // everyone's tile-t loads landed; slot (t-1)&3 free
    CFENCE;
    if (t + 3 < NT) issue(t + 3);
    compute(t);
  }
  WAITVM4;
  __builtin_amdgcn_s_barrier();
  CFENCE;
  compute(NT - 2);
  WAITVM0;
  __builtin_amdgcn_s_barrier();
  CFENCE;
  compute(NT - 1);
}

// ---------------------------------------------------------------------------
// K0: fp32 -> bf16 cast
// ---------------------------------------------------------------------------
__global__ __launch_bounds__(256) void k_cvt(const float* __restrict__ s,
                                             short* __restrict__ d, int n4)
{
  int i  = blockIdx.x * blockDim.x + threadIdx.x;
  int st = gridDim.x * blockDim.x;
  for (; i < n4; i += st) {
    float4 v = ((const float4*)s)[i];
    s16x4 o = { f2bf(v.x), f2bf(v.y), f2bf(v.z), f2bf(v.w) };
    ((s16x4*)d)[i] = o;
  }
}

// ---------------------------------------------------------------------------
// K1: QKV projection. C[m=(t*B+b), e] = sum_d Qb[m,d]*W[h,e,d] + bias[h,e]
// grid (8192/256=32, 512/256=2, 3*HG), 512 thr, 128 KiB dyn LDS
// ---------------------------------------------------------------------------
__global__ __launch_bounds__(512) void k_proj(
    const short* __restrict__ Qb,
    const short* __restrict__ Wqb, const short* __restrict__ Wkb, const short* __restrict__ Wvb,
    const float* __restrict__ bq, const float* __restrict__ bk, const float* __restrict__ bv,
    short* __restrict__ qb, short* __restrict__ kb, short* __restrict__ vb,
    int h0, int HG)
{
  extern __shared__ short lds[];
  const int bx = blockIdx.x, by = blockIdx.y, bz = blockIdx.z;
  const int p = bz / HG, hh = bz % HG, h = h0 + hh;

  const short* W    = (p == 0 ? Wqb : p == 1 ? Wkb : Wvb) + ((size_t)h * EH + (size_t)by * 256) * DIN;
  const float* bias = (p == 0 ? bq  : p == 1 ? bk  : bv ) + h * EH + by * 256;
  short* outp       = (p == 0 ? qb  : p == 1 ? kb  : vb ) + (size_t)hh * BATCH * T_SEQ * EH;
  const short* Ag   = Qb + (size_t)bx * 256 * DIN;

  f32x4_t acc[8][4] = {};
  gemm8w<DIN / 32>(Ag, DIN, W, DIN, lds, acc);

  const int lane = threadIdx.x & 63, wv = threadIdx.x >> 6;
  const int g = lane >> 4, r = lane & 15;
  const int Rw = (wv >> 2) * 128, Cw = (wv & 3) * 64;
#pragma unroll
  for (int ni = 0; ni < 4; ++ni) {
    int coll = Cw + ni * 16 + r;
    float bia = bias[coll];
    int e = by * 256 + coll;
#pragma unroll
    for (int mi = 0; mi < 8; ++mi) {
#pragma unroll
      for (int reg = 0; reg < 4; ++reg) {
        int m = bx * 256 + Rw + mi * 16 + g * 4 + reg;
        int t = m >> 3, b = m & 7;
        outp[((size_t)(b * T_SEQ + t)) * EH + e] = f2bf(acc[mi][ni][reg] + bia);
      }
    }
  }
}

// ---------------------------------------------------------------------------
// K3a: P[t,s] = exp(SCALE * q.k) bf16 + per-block column sums
// grid (1024/256=4, 4, HG*8), 512 thr
// colpart[(z*4 + bx)*T + s] = sum over this block's 256 t of exp
// ---------------------------------------------------------------------------
__global__ __launch_bounds__(512) void k_pgen(
    const short* __restrict__ qb, const short* __restrict__ kb,
    short* __restrict__ Pbuf, float* __restrict__ colpart)
{
  extern __shared__ short lds[];
  const int bx = blockIdx.x, by = blockIdx.y, z = blockIdx.z;
  const short* Ag = qb + (size_t)z * T_SEQ * EH + (size_t)bx * 256 * EH;
  const short* Bg = kb + (size_t)z * T_SEQ * EH + (size_t)by * 256 * EH;

  f32x4_t acc[8][4] = {};
  gemm8w<EH / 32>(Ag, EH, Bg, EH, lds, acc);

  short* Pb = Pbuf + (size_t)z * T_SEQ * T_SEQ;
  const int lane = threadIdx.x & 63, wv = threadIdx.x >> 6;
  const int g = lane >> 4, r = lane & 15;
  const int Rw = (wv >> 2) * 128, Cw = (wv & 3) * 64;

  float cs[4] = {0.f, 0.f, 0.f, 0.f};
#pragma unroll
  for (int ni = 0; ni < 4; ++ni) {
    int s = by * 256 + Cw + ni * 16 + r;
#pragma unroll
    for (int mi = 0; mi < 8; ++mi) {
#pragma unroll
      for (int reg = 0; reg < 4; ++reg) {
        int t = bx * 256 + Rw + mi * 16 + g * 4 + reg;
        float ev = __expf(acc[mi][ni][reg] * SCALE);
        cs[ni] += ev;
        Pb[(size_t)t * T_SEQ + s] = f2bf(ev);
      }
    }
  }
  // reduce over g groups (rows) within the wave, then across wave_m via LDS.
  // slot 0 of lds is safe to reuse: last read of slot 0 was tile NT-4.
#pragma unroll
  for (int ni = 0; ni < 4; ++ni) {
    cs[ni] += __shfl_xor(cs[ni], 16);
    cs[ni] += __shfl_xor(cs[ni], 32);
  }
  float* csL = (float*)lds;   // 2*256 floats, inside slot 0
  if (g == 0) {
#pragma unroll
    for (int ni = 0; ni < 4; ++ni) csL[(wv >> 2) * 256 + Cw + ni * 16 + r] = cs[ni];
  }
  __syncthreads();
  if (threadIdx.x < 256) {
    float tot = csL[threadIdx.x] + csL[256 + threadIdx.x];
    colpart[((size_t)z * 4 + bx) * T_SEQ + by * 256 + threadIdx.x] = tot;
  }
}

// ---------------------------------------------------------------------------
// K2': invs[z*T + s] = 1 / sum_tt colpart[(z*4+tt)*T + s]
// ---------------------------------------------------------------------------
__global__ __launch_bounds__(256) void k_invsum(const float* __restrict__ colpart,
                                                float* __restrict__ invs, int HB)
{
  int i = blockIdx.x * 256 + threadIdx.x;
  if (i < HB * T_SEQ) {
    int hb = i >> 10, s = i & (T_SEQ - 1);
    float sum = 0.f;
#pragma unroll
    for (int tt = 0; tt < 4; ++tt) sum += colpart[((size_t)hb * 4 + tt) * T_SEQ + s];
    invs[i] = 1.0f / sum;
  }
}

// ---------------------------------------------------------------------------
// K_tr: vbT[z][e][s] = vb[z][s][e] * invs[z][s]   (64x64 tiles via LDS)
// ---------------------------------------------------------------------------
__global__ __launch_bounds__(256) void k_tr(const short* __restrict__ vb,
                                            const float* __restrict__ invs,
                                            short* __restrict__ vbT)
{
  __shared__ float tl[64][65];
  const int bx = blockIdx.x, by = blockIdx.y, z = blockIdx.z;
  const short* in  = vb  + (size_t)z * T_SEQ * EH;
  short*       out = vbT + (size_t)z * EH * T_SEQ;
  const float* inv = invs + (size_t)z * T_SEQ;
  const int tid = threadIdx.x;

#pragma unroll
  for (int rep = 0; rep < 2; ++rep) {
    int s_l = (tid >> 3) + rep * 32;
    int e_l = (tid & 7) * 8;
    s16x8 v = *(const s16x8*)&in[(size_t)(bx * 64 + s_l) * EH + by * 64 + e_l];
    float iv = inv[bx * 64 + s_l];
#pragma unroll
    for (int j = 0; j < 8; ++j) tl[s_l][e_l + j] = bf2f(v[j]) * iv;
  }
  __syncthreads();
#pragma unroll
  for (int rep = 0; rep < 2; ++rep) {
    int e_w = (tid >> 3) + rep * 32;
    int s_w = (tid & 7) * 8;
    s16x8 o;
#pragma unroll
    for (int j = 0; j < 8; ++j) o[j] = f2bf(tl[s_w + j][e_w]);
    *(s16x8*)&out[(size_t)(by * 64 + e_w) * T_SEQ + bx * 64 + s_w] = o;
  }
}

// ---------------------------------------------------------------------------
// K3b: O[t,e] = sum_s P[t,s]*vbT[e,s] -> Hmat[t, b, h*EH + e] bf16
// grid (4, 2, HG*8), 512 thr
// ---------------------------------------------------------------------------
__global__ __launch_bounds__(512) void k_ogemm(
    const short* __restrict__ Pbuf, const short* __restrict__ vbT,
    short* __restrict__ Hmat, int h0)
{
  extern __shared__ short lds[];
  const int bx = blockIdx.x, by = blockIdx.y, z = blockIdx.z;
  const short* Ag = Pbuf + (size_t)z * T_SEQ * T_SEQ + (size_t)bx * 256 * T_SEQ;
  const short* Bg = vbT  + (size_t)z * EH * T_SEQ    + (size_t)by * 256 * T_SEQ;

  f32x4_t acc[8][4] = {};
  gemm8w<T_SEQ / 32>(Ag, T_SEQ, Bg, T_SEQ, lds, acc);

  const int hh = z >> 3, b = z & 7, h = h0 + hh;
  const int lane = threadIdx.x & 63, wv = threadIdx.x >> 6;
  const int g = lane >> 4, r = lane & 15;
  const int Rw = (wv >> 2) * 128, Cw = (wv & 3) * 64;
#pragma unroll
  for (int ni = 0; ni < 4; ++ni) {
    int e = by * 256 + Cw + ni * 16 + r;
#pragma unroll
    for (int mi = 0; mi < 8; ++mi) {
#pragma unroll
      for (int reg = 0; reg < 4; ++reg) {
        int t = bx * 256 + Rw + mi * 16 + g * 4 + reg;
        Hmat[((size_t)t * BATCH + b) * HE + (size_t)h * EH + e] = f2bf(acc[mi][ni][reg]);
      }
    }
  }
}

// ---------------------------------------------------------------------------
// K4a: split-K output GEMM. part[ks][m][d] = sum_{he in ks-slice} Hmat*Wo
// grid (32, 1, 8 ks), 512 thr; each block K=512 (NT=16)
// ---------------------------------------------------------------------------
__global__ __launch_bounds__(512) void k_final(
    const short* __restrict__ Hmat, const short* __restrict__ Wob,
    float* __restrict__ part)
{
  extern __shared__ short lds[];
  const int bx = blockIdx.x, ks = blockIdx.z;
  const short* Ag = Hmat + (size_t)bx * 256 * HE + (size_t)ks * 512;
  const short* Bg = Wob  + (size_t)ks * 512;

  f32x4_t acc[8][4] = {};
  gemm8w<512 / 32>(Ag, HE, Bg, HE, lds, acc);

  float* pp = part + (size_t)ks * (T_SEQ * BATCH) * DIN;
  const int lane = threadIdx.x & 63, wv = threadIdx.x >> 6;
  const int g = lane >> 4, r = lane & 15;
  const int Rw = (wv >> 2) * 128, Cw = (wv & 3) * 64;
#pragma unroll
  for (int ni = 0; ni < 4; ++ni) {
    int d = Cw + ni * 16 + r;
#pragma unroll
    for (int mi = 0; mi < 8; ++mi) {
#pragma unroll
      for (int reg = 0; reg < 4; ++reg) {
        int m = bx * 256 + Rw + mi * 16 + g * 4 + reg;
        pp[(size_t)m * DIN + d] = acc[mi][ni][reg];
      }
    }
  }
}

// K4b: out[m,d] = sum_ks part + bo[d]
__global__ __launch_bounds__(256) void k_red(const float* __restrict__ part,
                                             const float* __restrict__ bo,
                                             float* __restrict__ out)
{
  int i = blockIdx.x * 256 + threadIdx.x;     // over 8192*256/4 float4s
  float4 s = ((const float4*)part)[i];
#pragma unroll
  for (int ks = 1; ks < 8; ++ks) {
    float4 p = ((const float4*)(part + (size_t)ks * T_SEQ * BATCH * DIN))[i];
    s.x += p.x; s.y += p.y; s.z += p.z; s.w += p.w;
  }
  float4 b4 = ((const float4*)bo)[i & 63];
  s.x += b4.x; s.y += b4.y; s.z += b4.z; s.w += b4.w;
  ((float4*)out)[i] = s;
}

// ---------------------------------------------------------------------------
extern "C" void kernel_launch(void* const* d_in, const int* in_sizes, int n_in,
                              void* d_out, int out_size, void* d_ws, size_t ws_size,
                              hipStream_t stream)
{
  const float* Q  = (const float*)d_in[0];
  const float* Wq = (const float*)d_in[1];
  const float* bq = (const float*)d_in[2];
  const float* Wk = (const float*)d_in[3];
  const float* bk = (const float*)d_in[4];
  const float* Wv = (const float*)d_in[5];
  const float* bv = (const float*)d_in[6];
  const float* Wo = (const float*)d_in[7];
  const float* bo = (const float*)d_in[8];
  float* out = (float*)d_out;

  // opt into 128 KiB dynamic LDS for the 8-wave GEMM kernels (idempotent)
  (void)hipFuncSetAttribute((const void*)k_proj,  hipFuncAttributeMaxDynamicSharedMemorySize, 131072);
  (void)hipFuncSetAttribute((const void*)k_pgen,  hipFuncAttributeMaxDynamicSharedMemorySize, 131072);
  (void)hipFuncSetAttribute((const void*)k_ogemm, hipFuncAttributeMaxDynamicSharedMemorySize, 131072);
  (void)hipFuncSetAttribute((const void*)k_final, hipFuncAttributeMaxDynamicSharedMemorySize, 131072);

  // ---- workspace layout (bump allocator, 256B aligned) ----
  const size_t QB_B   = (size_t)T_SEQ * BATCH * DIN * 2;          //   4 MiB
  const size_t W_B    = (size_t)NH * EH * DIN * 2;                //   2 MiB each
  const size_t WO_B   = (size_t)DIN * HE * 2;                     //   2 MiB
  const size_t HMAT_B = (size_t)T_SEQ * BATCH * HE * 2;           //  64 MiB
  const size_t PART_B = (size_t)8 * T_SEQ * BATCH * DIN * 4;      //  64 MiB
  const size_t QKV_B  = (size_t)BATCH * T_SEQ * EH * 2;           //   8 MiB / head
  const size_t P_B    = (size_t)BATCH * T_SEQ * T_SEQ * 2;        //  16 MiB / head
  const size_t INV_B  = (size_t)BATCH * T_SEQ * 4;
  const size_t CP_B   = (size_t)BATCH * 4 * T_SEQ * 4;

  const size_t fixedB  = QB_B + 3 * W_B + WO_B + HMAT_B + PART_B;
  const size_t perHead = 4 * QKV_B + P_B + INV_B + CP_B;

  int HG = 8;
  while (HG > 1 && fixedB + (size_t)HG * perHead + 65536 > ws_size) HG >>= 1;

  char* w = (char*)d_ws;
  auto alloc = [&](size_t bytes) {
    char* p = w;
    w += (bytes + 255) & ~(size_t)255;
    return p;
  };
  short* Qb   = (short*)alloc(QB_B);
  short* Wqb  = (short*)alloc(W_B);
  short* Wkb  = (short*)alloc(W_B);
  short* Wvb  = (short*)alloc(W_B);
  short* Wob  = (short*)alloc(WO_B);
  short* Hmat = (short*)alloc(HMAT_B);
  float* part = (float*)alloc(PART_B);
  short* qb   = (short*)alloc((size_t)HG * QKV_B);
  short* kb   = (short*)alloc((size_t)HG * QKV_B);
  short* vb   = (short*)alloc((size_t)HG * QKV_B);
  short* vbT  = (short*)alloc((size_t)HG * QKV_B);
  short* Pbuf = (short*)alloc((size_t)HG * P_B);
  float* invs = (float*)alloc((size_t)HG * INV_B);
  float* cpart= (float*)alloc((size_t)HG * CP_B);

  // ---- casts ----
  k_cvt<<<dim3(2048), 256, 0, stream>>>(Q,  Qb,  T_SEQ * BATCH * DIN / 4);
  k_cvt<<<dim3(1024), 256, 0, stream>>>(Wq, Wqb, NH * EH * DIN / 4);
  k_cvt<<<dim3(1024), 256, 0, stream>>>(Wk, Wkb, NH * EH * DIN / 4);
  k_cvt<<<dim3(1024), 256, 0, stream>>>(Wv, Wvb, NH * EH * DIN / 4);
  k_cvt<<<dim3(1024), 256, 0, stream>>>(Wo, Wob, DIN * HE / 4);

  for (int h0 = 0; h0 < NH; h0 += HG) {
    k_proj  <<<dim3(32, 2, 3 * HG), 512, 131072, stream>>>(Qb, Wqb, Wkb, Wvb, bq, bk, bv,
                                                           qb, kb, vb, h0, HG);
    k_pgen  <<<dim3(4, 4, HG * BATCH), 512, 131072, stream>>>(qb, kb, Pbuf, cpart);
    k_invsum<<<dim3(HG * BATCH * T_SEQ / 256), 256, 0, stream>>>(cpart, invs, HG * BATCH);
    k_tr    <<<dim3(16, 8, HG * BATCH), 256, 0, stream>>>(vb, invs, vbT);
    k_ogemm <<<dim3(4, 2, HG * BATCH), 512, 131072, stream>>>(Pbuf, vbT, Hmat, h0);
  }
  k_final<<<dim3(32, 1, 8), 512, 131072, stream>>>(Hmat, Wob, part);
  k_red  <<<dim3(T_SEQ * BATCH * DIN / 4 / 256), 256, 0, stream>>>(part, bo, out);
}